// Round 11
// baseline (239.619 us; speedup 1.0000x reference)
//
#include <hip/hip_runtime.h>
#include <hip/hip_bf16.h>

using bf16 = __hip_bfloat16;
typedef __bf16 bf16x8 __attribute__((ext_vector_type(8)));
typedef float  f32x4  __attribute__((ext_vector_type(4)));

// Interface model (settled r0-r5): inputs fp32, output fp32.
// r6 382 -> r7 292 -> r8 242 -> r9 213.6 -> r10 212.8 (epilogue fix NEUTRAL:
// stores were absorbed, not limiting). r10 audit: k_qkv inner loop issues
// 32 ds_write_b32 (fp32->bf16 pack-transpose) per thread per iter -- LDS
// write-issue (~186 cyc) > MFMA (~154 cyc): LDS-instruction bound.
// r11: one-time prep pass (k_xt: x -> xT bf16 [B][N][C]; k_wcvt: W's -> bf16)
// so all GEMM staging becomes direct uint4 copies (8 b128 writes/thread/iter,
// zero pack VALU). att1 keeps runtime fp32 transpose (input is proj's output)
// but upgraded to 4x4 register transpose with b64 writes.
// MFMA 16x16x32 layouts (r6-r10 verified):
//   A-frag: lane holds A[m=lane&15][k=(lane>>4)*8+j] (row-major [m][k] tile)
//   B-frag: lane holds B[k][n=lane&15] (tile stored [n][k])
//   C/D:    row=4*(lane>>4)+reg, col=lane&15
// LDS tiles: XOR-swizzled 16B atoms (atom' = atom ^ (row&7)).

static constexpr int B  = 8;
static constexpr int C  = 512;
static constexpr int N  = 1024;   // H*W
static constexpr int NH = 8;
static constexpr int DH = 64;
static constexpr int CQ = 128;    // C/4

// ws layout (bytes), ~37.9 MB (r2/r4 ran a 54.6 MB envelope without fault):
static constexpr size_t QKV_OFF = 0;          // qkv bf16 [3][B,NH,N,DH] (o overwrites q)
static constexpr size_t H1_OFF  = 25165824;   // h1 bf16 [B,CQ,N]
static constexpr size_t XT_OFF  = 27262976;   // xT bf16 [B][N][C]   (8 MB)
static constexpr size_t WQ_OFF  = 35651584;   // Wqkv bf16 [1536][512]
static constexpr size_t WP_OFF  = 37224448;   // Wproj bf16 [512][512]
static constexpr size_t W1_OFF  = 37748736;   // Watt1 bf16 [128][512]

__device__ __forceinline__ unsigned pack2(float lo, float hi) {
  __hip_bfloat162 h = __float22bfloat162_rn(make_float2(lo, hi));
  return *(unsigned*)&h;
}
__device__ __forceinline__ int swz(int row, int col) {
  return row * 64 + ((((col >> 3) ^ row) & 7) << 3) + (col & 7);
}
__device__ __forceinline__ bf16x8 ldfrag(const short* tl, int row, int kk, int lane) {
  const int atom = 4 * kk + (lane >> 4);
  return *(const bf16x8*)&tl[row * 64 + (((atom ^ row) & 7) << 3)];
}
// fp32 64x64 tile, swizzled 16B atoms (4 floats)
__device__ __forceinline__ int fswz(int row, int col) {
  return row * 64 + ((((col >> 2) ^ row) & 15) << 2) + (col & 3);
}

// ---------------------------------------------------------------------------
// P0a: xT[b][p][c] = bf16(x[b][c][p])  -- LDS 64x64 transpose per block.
// ---------------------------------------------------------------------------
__global__ __launch_bounds__(256) void k_xt(const float* __restrict__ x,
                                            bf16* __restrict__ xT) {
  __shared__ float T[64 * 64];
  const int pt = blockIdx.x, ct = blockIdx.y, b = blockIdx.z;
  const int p0 = pt * 64, c0 = ct * 64;
  const int t = threadIdx.x;
  const float* src = &x[((size_t)b * C + c0) * N + p0];
#pragma unroll
  for (int i = 0; i < 4; ++i) {
    const int e = t + 256 * i;                 // 1024 float4
    const int row = e >> 4, q = e & 15;
    float4 v = *(const float4*)(src + (size_t)row * N + 4 * q);
    *(float4*)&T[fswz(row, 4 * q)] = v;
  }
  __syncthreads();
  bf16* dst = xT + ((size_t)b * N + p0) * C + c0;
#pragma unroll
  for (int i = 0; i < 2; ++i) {
    const int e = t + 256 * i;                 // 512 uint4
    const int prow = e >> 3, atom = e & 7;
    unsigned o[4];
#pragma unroll
    for (int j = 0; j < 4; ++j)
      o[j] = pack2(T[fswz(atom * 8 + 2 * j, prow)],
                   T[fswz(atom * 8 + 2 * j + 1, prow)]);
    *(uint4*)(dst + (size_t)prow * C + atom * 8) = *(uint4*)o;
  }
}

// ---------------------------------------------------------------------------
// P0b: convert Wqkv / Wproj / Watt1 fp32 -> bf16 (grid-strided by range).
// ---------------------------------------------------------------------------
__global__ __launch_bounds__(256) void k_wcvt(const float* __restrict__ Wq,
                                              const float* __restrict__ Wp,
                                              const float* __restrict__ W1,
                                              bf16* __restrict__ dq,
                                              bf16* __restrict__ dp,
                                              bf16* __restrict__ d1) {
  const int idx = blockIdx.x * 256 + threadIdx.x;   // float4 units, < 278528
  const float4* src; bf16* dst; int off;
  if (idx < 196608)      { src = (const float4*)Wq; dst = dq; off = idx; }
  else if (idx < 262144) { src = (const float4*)Wp; dst = dp; off = idx - 196608; }
  else                   { src = (const float4*)W1; dst = d1; off = idx - 262144; }
  float4 v = src[off];
  uint2 o = make_uint2(pack2(v.x, v.y), pack2(v.z, v.w));
  *(uint2*)(dst + 4 * (size_t)off) = o;
}

// ---------------------------------------------------------------------------
// K1 (MFMA 128x128, direct staging): qkv = W x -> q/k/v [B,NH,N,DH].
// D[m=o][n=p]: A = W bf16 tile [o][c] (Bl), B = xT tile [p][c] (Al).
// ---------------------------------------------------------------------------
__global__ __launch_bounds__(256, 3) void k_qkv(const bf16* __restrict__ Wq,
                                                const bf16* __restrict__ xT,
                                                bf16* __restrict__ qkv) {
  __shared__ __align__(16) short Al[128 * 64];  // xT [p][c]
  __shared__ __align__(16) short Bl[128 * 64];  // W  [o][c]
  const int pt = blockIdx.x, ot = blockIdx.y, b = blockIdx.z;
  const int p0 = pt * 128, o0 = ot * 128;
  const int t = threadIdx.x, l = t & 63, w = t >> 6;
  const int wo = w & 1, wp = w >> 1;
  const bf16* xTb = xT + ((size_t)b * N + p0) * C;
  const bf16* wb  = Wq + (size_t)o0 * C;
  const int srow = t >> 3, satom = t & 7;       // staging: 32 rows per iter-step
  uint4 rx[4], rw[4];
  auto ld = [&](int kc) {
#pragma unroll
    for (int i = 0; i < 4; ++i)
      rx[i] = *(const uint4*)(xTb + (size_t)(srow + 32 * i) * C + kc + satom * 8);
#pragma unroll
    for (int i = 0; i < 4; ++i)
      rw[i] = *(const uint4*)(wb + (size_t)(srow + 32 * i) * C + kc + satom * 8);
  };
  f32x4 acc[4][4] = {};
  ld(0);
  for (int kc = 0; kc < C; kc += 64) {
    __syncthreads();
#pragma unroll
    for (int i = 0; i < 4; ++i) {
      const int row = srow + 32 * i;
      *(uint4*)&Al[row * 64 + (((satom ^ row) & 7) << 3)] = rx[i];
      *(uint4*)&Bl[row * 64 + (((satom ^ row) & 7) << 3)] = rw[i];
    }
    __syncthreads();
    if (kc + 64 < C) ld(kc + 64);
#pragma unroll
    for (int kk = 0; kk < 2; ++kk) {
      bf16x8 af[4], bf[4];
#pragma unroll
      for (int i = 0; i < 4; ++i) af[i] = ldfrag(Bl, wo*64 + i*16 + (l&15), kk, l);
#pragma unroll
      for (int j = 0; j < 4; ++j) bf[j] = ldfrag(Al, wp*64 + j*16 + (l&15), kk, l);
#pragma unroll
      for (int i = 0; i < 4; ++i)
#pragma unroll
        for (int j = 0; j < 4; ++j)
          acc[i][j] = __builtin_amdgcn_mfma_f32_16x16x32_bf16(af[i], bf[j], acc[i][j], 0, 0, 0);
    }
  }
  // epilogue: acc -> [p][d] tiles in Al/Bl -> coalesced uint4 stores (r10)
  __syncthreads();
  {
    short* T = wo ? Bl : Al;
#pragma unroll
    for (int i = 0; i < 4; ++i) {
      const int d = i * 16 + 4 * (l >> 4);
#pragma unroll
      for (int j = 0; j < 4; ++j) {
        const int p = wp * 64 + j * 16 + (l & 15);
        *(unsigned*)&T[swz(p, d)]     = pack2(acc[i][j][0], acc[i][j][1]);
        *(unsigned*)&T[swz(p, d + 2)] = pack2(acc[i][j][2], acc[i][j][3]);
      }
    }
  }
  __syncthreads();
  {
    const int oc0 = o0, oc1 = o0 + 64;
    bf16* dst0 = qkv + (size_t)(oc0 >> 9) * (B * NH * N * DH) +
                 (size_t)(b * NH + ((oc0 >> 6) & 7)) * N * DH + (size_t)p0 * DH;
    bf16* dst1 = qkv + (size_t)(oc1 >> 9) * (B * NH * N * DH) +
                 (size_t)(b * NH + ((oc1 >> 6) & 7)) * N * DH + (size_t)p0 * DH;
#pragma unroll
    for (int it = 0; it < 8; ++it) {
      const int e = t + 256 * it;
      const int tile = e >> 10, row = (e >> 3) & 127, atom = e & 7;
      const short* T = tile ? Bl : Al;
      uint4 val = *(const uint4*)&T[row * 64 + (((atom ^ row) & 7) << 3)];
      bf16* dst = tile ? dst1 : dst0;
      *(uint4*)(dst + (size_t)row * DH + atom * 8) = val;
    }
  }
}

// ---------------------------------------------------------------------------
// K2 (MFMA flash attention, transposed): unchanged from r9/r10.
// ---------------------------------------------------------------------------
__global__ __launch_bounds__(256) void k_attn(bf16* __restrict__ qkv) {
  __shared__ __align__(16) short Ql[64 * 64];
  __shared__ __align__(16) short Kl[64 * 64];
  __shared__ __align__(16) short Vt[64 * 64];
  __shared__ __align__(16) short Pb[4 * 16 * 64];
  const int bh = blockIdx.x, qt = blockIdx.y;
  const int t = threadIdx.x, l = t & 63, w = t >> 6;
  const bf16* kp = qkv + (size_t)B * NH * N * DH;
  const bf16* vp = kp + (size_t)B * NH * N * DH;
  const uint4* gkb = (const uint4*)(kp + (size_t)bh * N * DH);
  const uint4* gvb = (const uint4*)(vp + (size_t)bh * N * DH);
  const int kpr = t & 31, g = t >> 5;

  {
    const uint4* gq = (const uint4*)(qkv + ((size_t)bh * N + qt * 64) * DH);
    for (int c = t; c < 512; c += 256) {
      int row = c >> 3, atom = c & 7;
      *(uint4*)&Ql[row * 64 + (((atom ^ row) & 7) << 3)] = gq[c];
    }
  }
  __syncthreads();
  bf16x8 qf[2] = { ldfrag(Ql, w * 16 + (l & 15), 0, l),
                   ldfrag(Ql, w * 16 + (l & 15), 1, l) };
  float m_run = -1e30f, l_run = 0.f;
  f32x4 oacc[4] = {};
  short* Pw = &Pb[w * 1024];

  union u4s { uint4 v; unsigned short s[8]; };
  uint4 kreg0, kreg1; u4s v0, v1;
  auto ld = [&](int mt) {
    const uint4* gk = gkb + mt * 512;
    kreg0 = gk[t]; kreg1 = gk[t + 256];
    const uint4* gv = gvb + mt * 512;
    v0.v = gv[16 * kpr + g]; v1.v = gv[16 * kpr + 8 + g];
  };
  ld(0);

  for (int mt = 0; mt < 16; ++mt) {
    __syncthreads();
    {
      const int r0 = t >> 3, a0 = t & 7;
      *(uint4*)&Kl[r0 * 64 + (((a0 ^ r0) & 7) << 3)] = kreg0;
      const int r1 = r0 + 32;
      *(uint4*)&Kl[r1 * 64 + (((a0 ^ r1) & 7) << 3)] = kreg1;
#pragma unroll
      for (int j = 0; j < 8; ++j)
        *(unsigned*)&Vt[swz(g * 8 + j, 2 * kpr)] =
            (unsigned)v0.s[j] | ((unsigned)v1.s[j] << 16);
    }
    __syncthreads();
    if (mt < 15) ld(mt + 1);
    f32x4 sacc[4] = {};
#pragma unroll
    for (int kk = 0; kk < 2; ++kk)
#pragma unroll
      for (int kt = 0; kt < 4; ++kt) {
        bf16x8 af = ldfrag(Kl, kt * 16 + (l & 15), kk, l);
        sacc[kt] = __builtin_amdgcn_mfma_f32_16x16x32_bf16(af, qf[kk], sacc[kt], 0, 0, 0);
      }
#pragma unroll
    for (int kt = 0; kt < 4; ++kt) sacc[kt] *= 0.125f;
    float smax = sacc[0][0];
#pragma unroll
    for (int kt = 0; kt < 4; ++kt)
#pragma unroll
      for (int r = 0; r < 4; ++r) smax = fmaxf(smax, sacc[kt][r]);
    smax = fmaxf(smax, __shfl_xor(smax, 16));
    smax = fmaxf(smax, __shfl_xor(smax, 32));
    const float mn = fmaxf(m_run, smax);
    const float alpha = __expf(m_run - mn);
    m_run = mn;
    float psum = 0.f;
    const int qr = l & 15, cb0 = 4 * (l >> 4);
#pragma unroll
    for (int kt = 0; kt < 4; ++kt) {
      float p0v = __expf(sacc[kt][0] - mn);
      float p1v = __expf(sacc[kt][1] - mn);
      float p2v = __expf(sacc[kt][2] - mn);
      float p3v = __expf(sacc[kt][3] - mn);
      psum += (p0v + p1v) + (p2v + p3v);
      const int cb = kt * 16 + cb0;
      *(unsigned*)&Pw[swz(qr, cb)]     = pack2(p0v, p1v);
      *(unsigned*)&Pw[swz(qr, cb + 2)] = pack2(p2v, p3v);
    }
    psum += __shfl_xor(psum, 16);
    psum += __shfl_xor(psum, 32);
    l_run = l_run * alpha + psum;
#pragma unroll
    for (int dt = 0; dt < 4; ++dt) oacc[dt] *= alpha;
#pragma unroll
    for (int kk = 0; kk < 2; ++kk) {
      bf16x8 pbf = ldfrag(Pw, l & 15, kk, l);
#pragma unroll
      for (int dt = 0; dt < 4; ++dt) {
        bf16x8 av = ldfrag(Vt, dt * 16 + (l & 15), kk, l);
        oacc[dt] = __builtin_amdgcn_mfma_f32_16x16x32_bf16(av, pbf, oacc[dt], 0, 0, 0);
      }
    }
  }
  __syncthreads();
  const float inv = 1.f / l_run;
  const int qr = l & 15, cb0 = 4 * (l >> 4);
#pragma unroll
  for (int dt = 0; dt < 4; ++dt) {
    const int cb = dt * 16 + cb0;
    *(unsigned*)&Pw[swz(qr, cb)]     = pack2(oacc[dt][0] * inv, oacc[dt][1] * inv);
    *(unsigned*)&Pw[swz(qr, cb + 2)] = pack2(oacc[dt][2] * inv, oacc[dt][3] * inv);
  }
  __syncthreads();
  bf16* obase = qkv + ((size_t)bh * N + qt * 64 + w * 16) * DH;
#pragma unroll
  for (int i = 0; i < 2; ++i) {
    const int e = l + 64 * i, row = e >> 3, atom = e & 7;
    uint4 val = *(const uint4*)&Pw[row * 64 + (((atom ^ row) & 7) << 3)];
    *(uint4*)(obase + (size_t)row * DH + atom * 8) = val;
  }
}

// ---------------------------------------------------------------------------
// K3 (MFMA): out = Wp o_rs + bias, fp32 out. Wp bf16 direct staging.
// ---------------------------------------------------------------------------
__global__ __launch_bounds__(256) void k_proj(const bf16* __restrict__ Wpb,
                                              const float* __restrict__ bp,
                                              const bf16* __restrict__ obuf,
                                              float* __restrict__ outd) {
  __shared__ __align__(16) short SM[8192];   // Wl | Ot ; epilogue fp32 64x64
  short* Wl = SM;
  short* Ot = SM + 4096;
  const int pt = blockIdx.x, ct = blockIdx.y, b = blockIdx.z;
  const int p0 = pt * 64, co0 = ct * 64;
  const int h = (p0 & 511) >> 6, eps = p0 >> 9;
  const int t = threadIdx.x, l = t & 63, w = t >> 6;
  const int cp = t & 31, g = t >> 5;
  const int srow = t >> 3, satom = t & 7;
  const bf16* wb = Wpb + (size_t)co0 * C;
  const bf16* obase = obuf + (size_t)(b * NH + h) * N * DH;
  union u4s { uint4 v; unsigned short s[8]; };
  uint4 rw[2]; u4s o0r, o1r;
  auto ld = [&](int kc) {
#pragma unroll
    for (int i = 0; i < 2; ++i)
      rw[i] = *(const uint4*)(wb + (size_t)(srow + 32 * i) * C + kc + satom * 8);
    const int ci0 = kc + 2 * cp;
    o0r.v = *(const uint4*)(obase + (size_t)(2 * ci0 + eps) * 64 + g * 8);
    o1r.v = *(const uint4*)(obase + (size_t)(2 * ci0 + 2 + eps) * 64 + g * 8);
  };
  f32x4 acc[4] = {};
  ld(0);
  for (int kc = 0; kc < C; kc += 64) {
    __syncthreads();
#pragma unroll
    for (int i = 0; i < 2; ++i) {
      const int row = srow + 32 * i;
      *(uint4*)&Wl[row * 64 + (((satom ^ row) & 7) << 3)] = rw[i];
    }
#pragma unroll
    for (int i = 0; i < 8; ++i)
      *(unsigned*)&Ot[swz(g * 8 + i, 2 * cp)] =
          (unsigned)o0r.s[i] | ((unsigned)o1r.s[i] << 16);
    __syncthreads();
    if (kc + 64 < C) ld(kc + 64);
    const int mrow = w * 16 + (l & 15);
#pragma unroll
    for (int kk = 0; kk < 2; ++kk) {
      bf16x8 a = ldfrag(Ot, mrow, kk, l);
#pragma unroll
      for (int nt = 0; nt < 4; ++nt) {
        bf16x8 bf = ldfrag(Wl, nt * 16 + (l & 15), kk, l);
        acc[nt] = __builtin_amdgcn_mfma_f32_16x16x32_bf16(a, bf, acc[nt], 0, 0, 0);
      }
    }
  }
  __syncthreads();
  {
    float* Ep = (float*)SM;
    const int pp = w * 16 + 4 * (l >> 4);
#pragma unroll
    for (int nt = 0; nt < 4; ++nt) {
      const int co = nt * 16 + (l & 15);
      const float bias = bp[co0 + co];
      *(float2*)&Ep[fswz(co, pp)]     = make_float2(acc[nt][0] + bias, acc[nt][1] + bias);
      *(float2*)&Ep[fswz(co, pp + 2)] = make_float2(acc[nt][2] + bias, acc[nt][3] + bias);
    }
  }
  __syncthreads();
  {
    const float* Ep = (const float*)SM;
#pragma unroll
    for (int it = 0; it < 4; ++it) {
      const int e = t + 256 * it;
      const int co = e >> 4, a = e & 15;
      float4 v = *(const float4*)&Ep[co * 64 + (((a ^ (co & 15)) & 15) << 2)];
      *(float4*)&outd[(size_t)b * C * N + (size_t)(co0 + co) * N + p0 + a * 4] = v;
    }
  }
}

// ---------------------------------------------------------------------------
// K4 (MFMA): h1 = relu(W1 out + b1), bf16 h1. W1 bf16 direct staging;
// out fp32 transpose via 4x4 register blocks + b64 writes.
// ---------------------------------------------------------------------------
__global__ __launch_bounds__(256) void k_att1(const bf16* __restrict__ W1b,
                                              const float* __restrict__ b1,
                                              const float* __restrict__ outd,
                                              bf16* __restrict__ h1b) {
  __shared__ __align__(16) short Wl[64 * 64];
  __shared__ __align__(16) short Xt[64 * 64];
  const int pt = blockIdx.x, jt = blockIdx.y, b = blockIdx.z;
  const int p0 = pt * 64, j0 = jt * 64;
  const int t = threadIdx.x, l = t & 63, w = t >> 6;
  const int srow = t >> 3, satom = t & 7;
  const int pb = t & 15, cg = t >> 4;   // x transpose: 4 p x 4 c per thread
  const bf16* wb = W1b + (size_t)j0 * C;
  const float* xsrc = &outd[(size_t)b * C * N + p0 + 4 * pb];
  uint4 rw[2]; float4 rx[4];
  auto ld = [&](int kc) {
#pragma unroll
    for (int i = 0; i < 2; ++i)
      rw[i] = *(const uint4*)(wb + (size_t)(srow + 32 * i) * C + kc + satom * 8);
#pragma unroll
    for (int j = 0; j < 4; ++j)
      rx[j] = *(const float4*)(xsrc + (size_t)(kc + 4 * cg + j) * N);
  };
  f32x4 acc[4] = {};
  ld(0);
  for (int kc = 0; kc < C; kc += 64) {
    __syncthreads();
#pragma unroll
    for (int i = 0; i < 2; ++i) {
      const int row = srow + 32 * i;
      *(uint4*)&Wl[row * 64 + (((satom ^ row) & 7) << 3)] = rw[i];
    }
#pragma unroll
    for (int r = 0; r < 4; ++r) {
      const float* f = (const float*)rx;        // rx[j][r] = f[4*j + r]
      unsigned d0 = pack2(f[r], f[4 + r]);
      unsigned d1 = pack2(f[8 + r], f[12 + r]);
      uint2 dv = make_uint2(d0, d1);
      *(uint2*)&Xt[swz(4 * pb + r, 4 * cg)] = dv;
    }
    __syncthreads();
    if (kc + 64 < C) ld(kc + 64);
    const int mrow = w * 16 + (l & 15);
#pragma unroll
    for (int kk = 0; kk < 2; ++kk) {
      bf16x8 a = ldfrag(Xt, mrow, kk, l);
#pragma unroll
      for (int nt = 0; nt < 4; ++nt) {
        bf16x8 bf = ldfrag(Wl, nt * 16 + (l & 15), kk, l);
        acc[nt] = __builtin_amdgcn_mfma_f32_16x16x32_bf16(a, bf, acc[nt], 0, 0, 0);
      }
    }
  }
  __syncthreads();
  {
    const int pp = w * 16 + 4 * (l >> 4);
#pragma unroll
    for (int nt = 0; nt < 4; ++nt) {
      const int jo = nt * 16 + (l & 15);
      const float bias = b1[j0 + jo];
      float v0 = fmaxf(acc[nt][0] + bias, 0.f), v1 = fmaxf(acc[nt][1] + bias, 0.f);
      float v2 = fmaxf(acc[nt][2] + bias, 0.f), v3 = fmaxf(acc[nt][3] + bias, 0.f);
      *(unsigned*)&Wl[swz(jo, pp)]     = pack2(v0, v1);
      *(unsigned*)&Wl[swz(jo, pp + 2)] = pack2(v2, v3);
    }
  }
  __syncthreads();
#pragma unroll
  for (int it = 0; it < 2; ++it) {
    const int e = t + 256 * it;
    const int row = e >> 3, atom = e & 7;
    uint4 val = *(const uint4*)&Wl[row * 64 + (((atom ^ row) & 7) << 3)];
    *(uint4*)((bf16*)h1b + (size_t)b * CQ * N + (size_t)(j0 + row) * N + p0 + atom * 8) = val;
  }
}

// ---------------------------------------------------------------------------
// K5 (fused att2+sigmoid+gate): unchanged.
// ---------------------------------------------------------------------------
__global__ __launch_bounds__(256) void k_gate(const float* __restrict__ W2,
                                              const float* __restrict__ b2,
                                              const bf16* __restrict__ h1b,
                                              float* __restrict__ out0,
                                              float* __restrict__ out1) {
  __shared__ float red[8][32];
  __shared__ __align__(16) float att[32];
  const int blk = blockIdx.x, t = threadIdx.x;
  const int b = blk >> 5, p0 = (blk & 31) * 32;
  const int pl = t & 31, jg = t >> 5;
  float acc = 0.f;
  const bf16* hb = h1b + ((size_t)b * CQ + jg * 16) * N + p0 + pl;
#pragma unroll
  for (int jj = 0; jj < 16; ++jj)
    acc += W2[jg * 16 + jj] * __bfloat162float(hb[(size_t)jj * N]);
  red[jg][pl] = acc;
  __syncthreads();
  if (t < 32) {
    float a = b2[0];
#pragma unroll
    for (int k = 0; k < 8; ++k) a += red[k][t];
    const float sg = 1.f / (1.f + __expf(-a));
    att[t] = sg;
    out1[b * N + p0 + t] = sg;
  }
  __syncthreads();
  const int p4 = t & 7, cc = t >> 3;
  float4* ob4 = (float4*)(out0 + (size_t)b * C * N + p0);
  const float4 sg4 = *(const float4*)&att[4 * p4];
  for (int c = cc; c < C; c += 32) {
    float4 v = ob4[c * 256 + p4];
    v.x *= sg4.x; v.y *= sg4.y; v.z *= sg4.z; v.w *= sg4.w;
    ob4[c * 256 + p4] = v;
  }
}

// ---------------------------------------------------------------------------
extern "C" void kernel_launch(void* const* d_in, const int* in_sizes, int n_in,
                              void* d_out, int out_size, void* d_ws, size_t ws_size,
                              hipStream_t stream) {
  const float* x     = (const float*)d_in[0];
  const float* Wqkv  = (const float*)d_in[1];
  const float* Wproj = (const float*)d_in[2];
  const float* bproj = (const float*)d_in[3];
  const float* Watt1 = (const float*)d_in[4];
  const float* batt1 = (const float*)d_in[5];
  const float* Watt2 = (const float*)d_in[6];
  const float* batt2 = (const float*)d_in[7];

  char* ws = (char*)d_ws;
  bf16* qkvb = (bf16*)(ws + QKV_OFF);
  bf16* h1b  = (bf16*)(ws + H1_OFF);
  bf16* xTb  = (bf16*)(ws + XT_OFF);
  bf16* Wqb  = (bf16*)(ws + WQ_OFF);
  bf16* Wpb  = (bf16*)(ws + WP_OFF);
  bf16* W1b  = (bf16*)(ws + W1_OFF);

  float* out0 = (float*)d_out;
  float* out1 = out0 + (size_t)B * C * N;   // 4194304 floats

  k_xt  <<<dim3(16, 8, 8), 256, 0, stream>>>(x, xTb);
  k_wcvt<<<1088, 256, 0, stream>>>(Wqkv, Wproj, Watt1, Wqb, Wpb, W1b);
  k_qkv <<<dim3(8, 12, 8), 256, 0, stream>>>(Wqb, xTb, qkvb);
  k_attn<<<dim3(64, 16),   256, 0, stream>>>(qkvb);
  k_proj<<<dim3(16, 8, 8), 256, 0, stream>>>(Wpb, bproj, qkvb, out0);
  k_att1<<<dim3(16, 2, 8), 256, 0, stream>>>(W1b, batt1, out0, h1b);
  k_gate<<<256, 256, 0, stream>>>(Watt2, batt2, h1b, out0, out1);
}